// Round 12
// baseline (169.270 us; speedup 1.0000x reference)
//
#include <hip/hip_runtime.h>
#include <hip/hip_bf16.h>

#define NV 16384
#define NC 16
#define NL 6
#define ND 64

typedef unsigned short u16;
typedef unsigned int u32;
typedef __attribute__((ext_vector_type(8))) short short8;
typedef __attribute__((ext_vector_type(4))) float f32x4;

// ---- pbuf (fp32) offsets, pbuf = (float*)((char*)ws + 256) ----
#define PB_BN  0
#define PB_FE  64
#define PB_B1V 128
#define PB_B2V 192
#define PB_B1C 256
#define PB_B2C 320
// ---- bf16 regions, offsets in u16 elements from (u16*)ws ----
// BVS: clause-B swizzled [gk(12)][nt(8)][lane(64)][8]; elem = Wsrc[k][n]:
//   k = gk*32 + (lane>>4)*8 + j; n = (lane&15)*4 + (nt&3); src = nt<4 ? W1v : W2v
#define U_BVS   896       // 49152
// BCS: var-B swizzled [ks(32)][nt(8)][lane(64)][8]; n = nt*16+(lane&15) style (old)
#define U_BCS   50048     // 131072
#define U_VARSB 185216    // [NV+1][64] bf16 vars; row NV = false_emb
#define U_NEGB  1233856   // [NV+1][64] bf16 negvar; row NV = true_emb
#define U_FIDX  2282496   // [NV][96] u16 fused row index (c*6+l)

__device__ __forceinline__ float ldbf(const u16* p, int i) {
  return __uint_as_float(((u32)p[i]) << 16);
}
__device__ __forceinline__ u16 f2b(float f) {  // RNE f32->bf16
  u32 x = __float_as_uint(f);
  return (u16)((x + 0x7FFF + ((x >> 16) & 1)) >> 16);
}
__device__ __forceinline__ int ldmask(const void* p, int i, int bdt) {
  return bdt ? (int)((const signed char*)p)[i] : ((const int*)p)[i];
}
__device__ __forceinline__ float ldf(const void* p, int i, int fdt) {
  return fdt ? ldbf((const u16*)p, i) : ((const float*)p)[i];
}
__device__ __forceinline__ void gll16(const u16* g, u16* l) {
  __builtin_amdgcn_global_load_lds(
      (const __attribute__((address_space(1))) u32*)(g),
      (__attribute__((address_space(3))) u32*)(l), 16, 0, 0);
}

// ---------- merged prep ----------
// bid 0: flags+params; 1..24: BVS; 25..88: BCS; 89..216: cvt; 217..600: fidx; 601..857: negvar
__global__ __launch_bounds__(256) void k_prep(
    const void* vars, const int* __restrict__ lits, const void* negm, const void* vval,
    const void* Wn, const void* bn, const void* femb,
    const void* W1v, const void* b1v, const void* W2v, const void* b2v,
    const void* W1c, const void* b1c, const void* W2c, const void* b2c,
    int* flags, float* pbuf, u16* wsB) {
  __shared__ int s_cnt[4], s_big[4];
  __shared__ __align__(16) u16 BnL[4096];
  const int t = threadIdx.x;
  {
    const u32 w = ((const u32*)vars)[t];
    const u32 e = (w >> 7) & 0xFF;
    const unsigned long long bal = __ballot(e >= 0x6E && e <= 0x8E);
    const u32 bw = ((const u32*)vval)[t];
    const unsigned long long bb = __ballot(bw > 1u);
    if ((t & 63) == 0) { s_cnt[t >> 6] = __popcll(bal); s_big[t >> 6] = (bb != 0ull); }
  }
  __syncthreads();
  const int fdt = (s_cnt[0] + s_cnt[1] + s_cnt[2] + s_cnt[3]) >= 192;
  const int bdt = (s_big[0] | s_big[1] | s_big[2] | s_big[3]);
  const int bid = blockIdx.x;

  if (bid == 0) {
    if (t == 0) { flags[0] = fdt; flags[1] = bdt; }
    if (t < 64) {
      const void* src[6] = {bn, femb, b1v, b2v, b1c, b2c};
      const int off[6] = {PB_BN, PB_FE, PB_B1V, PB_B2V, PB_B1C, PB_B2C};
      for (int j = 0; j < 6; j++) pbuf[off[j] + t] = ldf(src[j], t, fdt);
      wsB[U_VARSB + NV * 64 + t] = fdt ? ((const u16*)femb)[t] : f2b(((const float*)femb)[t]);
    }
  } else if (bid < 25) {
    const int c = (bid - 1) * 256 + t;            // 0..6143
    const int ln = c & 63, nt = (c >> 6) & 7, ks = c >> 9;  // ks 0..11
    const void* src = (nt < 4) ? W1v : W2v;
    const int n6 = (ln & 15) * 4 + (nt & 3);      // new d-mapping
    const int kb = ks * 32 + (ln >> 4) * 8;
    u16 o[8];
#pragma unroll
    for (int j = 0; j < 8; j++) o[j] = f2b(ldf(src, (kb + j) * 64 + n6, fdt));
    *(short8*)(wsB + U_BVS + c * 8) = *(short8*)o;
  } else if (bid < 89) {
    const int c = (bid - 25) * 256 + t;           // 0..16383
    const int ln = c & 63, nt = (c >> 6) & 7, ks = c >> 9;  // ks 0..31
    const int n = nt * 16 + (ln & 15);
    const void* src = (n < 64) ? W1c : W2c;
    const int kb = ks * 32 + (ln >> 4) * 8, n6 = n & 63;
    u16 o[8];
#pragma unroll
    for (int j = 0; j < 8; j++) o[j] = f2b(ldf(src, (kb + j) * 64 + n6, fdt));
    *(short8*)(wsB + U_BCS + c * 8) = *(short8*)o;
  } else if (bid < 217) {
    const int c8 = ((bid - 89) * 256 + t) * 4;
#pragma unroll
    for (int cc = 0; cc < 4; cc++) {
      u16 o[8];
      if (fdt) {
        *(short8*)o = ((const short8*)vars)[c8 + cc];
      } else {
        const float* f = (const float*)vars + (c8 + cc) * 8;
#pragma unroll
        for (int j = 0; j < 8; j++) o[j] = f2b(f[j]);
      }
      *(short8*)(wsB + U_VARSB + (c8 + cc) * 8) = *(short8*)o;
    }
  } else if (bid < 601) {
    const int i0 = ((bid - 217) * 256 + t) * 16;
    u16 o[16];
    if (!bdt) {
      const int4* lp = (const int4*)(lits + i0);
      const int4* vp = (const int4*)((const int*)vval + i0);
      const int4* np = (const int4*)((const int*)negm + i0);
#pragma unroll
      for (int c4 = 0; c4 < 4; c4++) {
        const int4 L = lp[c4], V = vp[c4], N = np[c4];
        o[c4 * 4 + 0] = (u16)(V.x ? (L.x + (N.x ? (NV + 1) : 0)) : NV);
        o[c4 * 4 + 1] = (u16)(V.y ? (L.y + (N.y ? (NV + 1) : 0)) : NV);
        o[c4 * 4 + 2] = (u16)(V.z ? (L.z + (N.z ? (NV + 1) : 0)) : NV);
        o[c4 * 4 + 3] = (u16)(V.w ? (L.w + (N.w ? (NV + 1) : 0)) : NV);
      }
    } else {
#pragma unroll
      for (int j = 0; j < 16; j++) {
        const int i = i0 + j;
        const int valid = ldmask(vval, i, bdt);
        const int neg = ldmask(negm, i, bdt);
        o[j] = (u16)(valid ? (lits[i] + (neg ? (NV + 1) : 0)) : NV);
      }
    }
    *(short8*)(wsB + U_FIDX + i0) = *(short8*)o;
    *(short8*)(wsB + U_FIDX + i0 + 8) = *(short8*)(o + 8);
  } else {
    // negvar
    const int lane = t & 63, wv = t >> 6;
    const int col = lane & 15, quad = lane >> 4, q8 = quad * 8;
    const int rowbase = (bid - 601) * 64 + wv * 16;
    for (int i = t; i < 4096; i += 256) {
      const int n = i >> 6, k = i & 63;
      BnL[i] = f2b(ldf(Wn, k * 64 + n, fdt));
    }
    __syncthreads();
    const int arow = min(rowbase + col, NV);
    short8 a[2];
    if (fdt) {
      const u16* src = (arow == NV) ? (const u16*)femb : (const u16*)vars + arow * 64;
      a[0] = *(const short8*)(src + q8);
      a[1] = *(const short8*)(src + 32 + q8);
    } else {
      const float* src = (arow == NV) ? (const float*)femb : (const float*)vars + arow * 64;
      u16 tmp[16];
#pragma unroll
      for (int j = 0; j < 8; j++) tmp[j] = f2b(src[q8 + j]);
#pragma unroll
      for (int j = 0; j < 8; j++) tmp[8 + j] = f2b(src[32 + q8 + j]);
      a[0] = *(short8*)tmp;
      a[1] = *(short8*)(tmp + 8);
    }
    f32x4 acc[4];
#pragma unroll
    for (int nt = 0; nt < 4; nt++) acc[nt] = (f32x4){0.f, 0.f, 0.f, 0.f};
#pragma unroll
    for (int ks = 0; ks < 2; ks++) {
#pragma unroll
      for (int nt = 0; nt < 4; nt++) {
        const short8 b = *(const short8*)(BnL + (nt * 16 + col) * 64 + ks * 32 + q8);
        acc[nt] = __builtin_amdgcn_mfma_f32_16x16x32_bf16(a[ks], b, acc[nt], 0, 0, 0);
      }
    }
#pragma unroll
    for (int reg = 0; reg < 4; reg++) {
      const int r = rowbase + quad * 4 + reg;
      if (r <= NV) {
#pragma unroll
        for (int nt = 0; nt < 4; nt++) {
          const int d = nt * 16 + col;
          wsB[U_NEGB + r * 64 + d] = f2b(acc[nt][reg] + ldf(bn, d, fdt));
        }
      }
    }
  }
}

// ---------- fused combiner: 512 threads, 8 waves, 4 vars/wave = 32 vars/block ----------
__global__ __launch_bounds__(512, 1) void k_main(
    const void* __restrict__ vars, const void* __restrict__ cval,
    const float* __restrict__ pbuf, const int* __restrict__ flags,
    const u16* __restrict__ wsB, void* __restrict__ outv) {
  // phase 1: smem[0..24575] = B double-buffer [2][12288] (48 KB)
  // phase 2: smem = clause_emb [grp(2)][ks(32)][lane(64)][8] (64 KB)
  __shared__ __align__(16) u16 smem[32768];
  __shared__ float ps[32][4];
  __shared__ int hcS[32];

  const int tid = threadIdx.x, lane = tid & 63, wv = tid >> 6;
  const int col = lane & 15, quad = lane >> 4, q8 = quad * 8;
  const int fdt = flags[0], bdt = flags[1];
  const int vbase = blockIdx.x * 32 + wv * 4;
  const int v0 = blockIdx.x * 32;

  u32 r2_[4][3];
#pragma unroll
  for (int v4 = 0; v4 < 4; v4++)
#pragma unroll
    for (int i = 0; i < 3; i++)
      r2_[v4][i] = *(const u32*)(wsB + U_FIDX + (vbase + v4) * 96 + col * 6 + i * 2);

  const int cv = ldmask(cval, vbase * 16 + lane, bdt);
  const unsigned long long bal = __ballot(cv != 0);
  if (lane < 4) hcS[wv * 4 + lane] = ((bal >> (lane * 16)) & 0xFFFFull) != 0;

  f32x4 acc[4][8];
#pragma unroll
  for (int v4 = 0; v4 < 4; v4++)
#pragma unroll
    for (int nt = 0; nt < 8; nt++) acc[v4][nt] = (f32x4){0.f, 0.f, 0.f, 0.f};

  // stage quarter 0 into buf 0: 24 chunks of 1 KB, 3 per wave
#pragma unroll
  for (int j = 0; j < 3; j++) {
    const int cl = wv * 3 + j;
    gll16(wsB + U_BVS + cl * 512 + lane * 8, &smem[cl * 512]);
  }
  short8 a_cur[4], a_nxt[4];
#pragma unroll
  for (int v4 = 0; v4 < 4; v4++) {
    const int idx = (int)(r2_[v4][0] & 0xFFFFu);
    a_cur[v4] = *(const short8*)(wsB + U_VARSB + idx * 64 + q8);
  }
  __syncthreads();

  for (int q = 0; q < 4; q++) {
    if (q < 3) {
#pragma unroll
      for (int j = 0; j < 3; j++) {
        const int cl = wv * 3 + j;
        gll16(wsB + U_BVS + (q + 1) * 12288 + cl * 512 + lane * 8,
              &smem[((q + 1) & 1) * 12288 + cl * 512]);
      }
    }
#pragma unroll
    for (int ksl = 0; ksl < 3; ksl++) {
      const int gk = q * 3 + ksl;
      if (gk < 11) {
        const int gn = gk + 1;
        const int goff = (gn & 1) * 32 + q8;
        const int pi = gn >> 2, ph = (gn >> 1) & 1;
#pragma unroll
        for (int v4 = 0; v4 < 4; v4++) {
          const int idx = (int)((r2_[v4][pi] >> (ph * 16)) & 0xFFFFu);
          a_nxt[v4] = *(const short8*)(wsB + U_VARSB + idx * 64 + goff);
        }
      }
#pragma unroll
      for (int nt = 0; nt < 8; nt++) {
        const short8 b = *(const short8*)(&smem[(q & 1) * 12288 + (ksl * 8 + nt) * 512 + lane * 8]);
#pragma unroll
        for (int v4 = 0; v4 < 4; v4++)
          acc[v4][nt] = __builtin_amdgcn_mfma_f32_16x16x32_bf16(a_cur[v4], b, acc[v4][nt], 0, 0, 0);
      }
#pragma unroll
      for (int v4 = 0; v4 < 4; v4++) a_cur[v4] = a_nxt[v4];
    }
    if (q < 3) __syncthreads();
  }
  __syncthreads();  // done reading B before epilogue overwrites smem

  // phase-1 epilogue: lane holds d = col*4 + jj (jj 0..3), both C1 (nt=jj) and C2 (nt=jj+4)
  {
    const float4 b1l = *(const float4*)(pbuf + PB_B1V + col * 4);
    const float4 b2l = *(const float4*)(pbuf + PB_B2V + col * 4);
    float truel[4];
#pragma unroll
    for (int jj = 0; jj < 4; jj++) truel[jj] = ldbf(wsB, U_NEGB + NV * 64 + col * 4 + jj);
    const int grp = wv >> 2;
    const int vloc = (wv & 3) * 4;
#pragma unroll
    for (int v4 = 0; v4 < 4; v4++) {
      const u32 vmask = (u32)((bal >> (v4 * 16)) & 0xFFFFull);
#pragma unroll
      for (int reg = 0; reg < 4; reg++) {
        const int c = quad * 4 + reg;
        float hh[4], ss = 0.f;
        hh[0] = 1.0f / (1.0f + __expf(-(acc[v4][0][reg] + b1l.x))) + acc[v4][4][reg] + b2l.x;
        hh[1] = 1.0f / (1.0f + __expf(-(acc[v4][1][reg] + b1l.y))) + acc[v4][5][reg] + b2l.y;
        hh[2] = 1.0f / (1.0f + __expf(-(acc[v4][2][reg] + b1l.z))) + acc[v4][6][reg] + b2l.z;
        hh[3] = 1.0f / (1.0f + __expf(-(acc[v4][3][reg] + b1l.w))) + acc[v4][7][reg] + b2l.w;
#pragma unroll
        for (int jj = 0; jj < 4; jj++) ss += hh[jj] * hh[jj];
        ss += __shfl_xor(ss, 1, 64); ss += __shfl_xor(ss, 2, 64);
        ss += __shfl_xor(ss, 4, 64); ss += __shfl_xor(ss, 8, 64);
        const float sc = rsqrtf(ss);
        const int valid = (vmask >> c) & 1;
        ushort4 pk;
        pk.x = f2b(valid ? hh[0] * sc : truel[0]);
        pk.y = f2b(valid ? hh[1] * sc : truel[1]);
        pk.z = f2b(valid ? hh[2] * sc : truel[2]);
        pk.w = f2b(valid ? hh[3] * sc : truel[3]);
        // k = c*64 + col*4 + jj  ->  ks = c*2+(col>>3); lane = ((col>>1)&3)*16+vloc+v4; j = (col&1)*4+jj
        const int addr = grp * 16384 + (c * 2 + (col >> 3)) * 512 +
                         (((col >> 1) & 3) * 16 + vloc + v4) * 8 + (col & 1) * 4;
        *(ushort4*)(&smem[addr]) = pk;
      }
    }
  }
  __syncthreads();

  // phase 2: waves 0..3 only; wave nq computes d = nq*16+col for BOTH 16-var groups
  float h0[4], h1[4];
  if (wv < 4) {
    const int nq = wv;
    f32x4 a00 = (f32x4){0.f, 0.f, 0.f, 0.f}, a01 = a00, a10 = a00, a11 = a00;
#pragma unroll 8
    for (int ks = 0; ks < 32; ks++) {
      const short8 a0 = *(const short8*)(&smem[ks * 512 + lane * 8]);
      const short8 a1 = *(const short8*)(&smem[16384 + ks * 512 + lane * 8]);
      const short8 b1 = *(const short8*)(wsB + U_BCS + (ks * 8 + nq) * 512 + lane * 8);
      const short8 b2 = *(const short8*)(wsB + U_BCS + (ks * 8 + nq + 4) * 512 + lane * 8);
      a00 = __builtin_amdgcn_mfma_f32_16x16x32_bf16(a0, b1, a00, 0, 0, 0);
      a01 = __builtin_amdgcn_mfma_f32_16x16x32_bf16(a0, b2, a01, 0, 0, 0);
      a10 = __builtin_amdgcn_mfma_f32_16x16x32_bf16(a1, b1, a10, 0, 0, 0);
      a11 = __builtin_amdgcn_mfma_f32_16x16x32_bf16(a1, b2, a11, 0, 0, 0);
    }
    const int d = nq * 16 + col;
    const float b1c_d = pbuf[PB_B1C + d], b2c_d = pbuf[PB_B2C + d];
#pragma unroll
    for (int reg = 0; reg < 4; reg++) {
      h0[reg] = 1.0f / (1.0f + __expf(-(a00[reg] + b1c_d))) + a01[reg] + b2c_d;
      h1[reg] = 1.0f / (1.0f + __expf(-(a10[reg] + b1c_d))) + a11[reg] + b2c_d;
      float s0 = h0[reg] * h0[reg], s1 = h1[reg] * h1[reg];
      s0 += __shfl_xor(s0, 1, 64); s0 += __shfl_xor(s0, 2, 64);
      s0 += __shfl_xor(s0, 4, 64); s0 += __shfl_xor(s0, 8, 64);
      s1 += __shfl_xor(s1, 1, 64); s1 += __shfl_xor(s1, 2, 64);
      s1 += __shfl_xor(s1, 4, 64); s1 += __shfl_xor(s1, 8, 64);
      if (col == 0) {
        ps[quad * 4 + reg][nq] = s0;
        ps[16 + quad * 4 + reg][nq] = s1;
      }
    }
  }
  __syncthreads();
  if (wv < 4) {
    const int d = wv * 16 + col;
#pragma unroll
    for (int reg = 0; reg < 4; reg++) {
#pragma unroll
      for (int g = 0; g < 2; g++) {
        const int r = g * 16 + quad * 4 + reg;
        const float tot = ps[r][0] + ps[r][1] + ps[r][2] + ps[r][3];
        const float hv = g ? h1[reg] : h0[reg];
        float o = hv * rsqrtf(tot);
        const int oi = (v0 + r) * 64 + d;
        if (hcS[r]) {
          if (fdt) ((u16*)outv)[oi] = f2b(o);
          else ((float*)outv)[oi] = o;
        } else {
          if (fdt) ((u16*)outv)[oi] = ((const u16*)vars)[oi];
          else ((float*)outv)[oi] = ((const float*)vars)[oi];
        }
      }
    }
  }
}

extern "C" void kernel_launch(void* const* d_in, const int* in_sizes, int n_in,
                              void* d_out, int out_size, void* d_ws, size_t ws_size,
                              hipStream_t stream) {
  const void* vars = d_in[0];
  const int* lits = (const int*)d_in[1];
  const void* negm = d_in[2];
  const void* vval = d_in[3];
  const void* cvalid = d_in[4];
  const void* Wn = d_in[5];
  const void* bn = d_in[6];
  const void* femb = d_in[7];
  const void* W1v = d_in[8];
  const void* b1v = d_in[9];
  const void* W2v = d_in[10];
  const void* b2v = d_in[11];
  const void* W1c = d_in[12];
  const void* b1c = d_in[13];
  const void* W2c = d_in[14];
  const void* b2c = d_in[15];

  int* flags = (int*)d_ws;
  float* pbuf = (float*)((char*)d_ws + 256);
  u16* wsB = (u16*)d_ws;

  k_prep<<<858, 256, 0, stream>>>(vars, lits, negm, vval, Wn, bn, femb,
                                  W1v, b1v, W2v, b2v, W1c, b1c, W2c, b2c,
                                  flags, pbuf, wsB);
  k_main<<<NV / 32, 512, 0, stream>>>(vars, cvalid, pbuf, flags, wsB, d_out);
}

// Round 13
// 159.938 us; speedup vs baseline: 1.0583x; 1.0583x over previous
//
#include <hip/hip_runtime.h>
#include <hip/hip_bf16.h>

#define NV 16384
#define NC 16
#define NL 6
#define ND 64

typedef unsigned short u16;
typedef unsigned int u32;
typedef __attribute__((ext_vector_type(8))) short short8;
typedef __attribute__((ext_vector_type(4))) float f32x4;

// ---- pbuf (fp32) offsets, pbuf = (float*)((char*)ws + 256) ----
#define PB_BN  0
#define PB_FE  64
#define PB_B1V 128
#define PB_B2V 192
#define PB_B1C 256
#define PB_B2C 320
// ---- bf16 regions, offsets in u16 elements from (u16*)ws ----
// BVS: clause-B swizzled [gk(12)][nt(8)][lane(64)][8]; elem = W{1,2}v[k][n&63]:
//   k = gk*32+(lane>>4)*8+j; n = nt*16+(lane&15); src = nt<4 ? W1v : W2v
#define U_BVS   896       // 49152
// BCS: var-B swizzled [ks(32)][nt(8)][lane(64)][8]; same mapping, W1c/W2c
#define U_BCS   50048     // 131072
#define U_VARSB 185216    // [NV+1][64] bf16 vars; row NV = false_emb
#define U_NEGB  1233856   // [NV+1][64] bf16 negvar; row NV = true_emb
#define U_FIDX  2282496   // [NV][96] u16 fused row index (c*6+l)

__device__ __forceinline__ float ldbf(const u16* p, int i) {
  return __uint_as_float(((u32)p[i]) << 16);
}
__device__ __forceinline__ u16 f2b(float f) {  // RNE f32->bf16
  u32 x = __float_as_uint(f);
  return (u16)((x + 0x7FFF + ((x >> 16) & 1)) >> 16);
}
__device__ __forceinline__ int ldmask(const void* p, int i, int bdt) {
  return bdt ? (int)((const signed char*)p)[i] : ((const int*)p)[i];
}
__device__ __forceinline__ float ldf(const void* p, int i, int fdt) {
  return fdt ? ldbf((const u16*)p, i) : ((const float*)p)[i];
}
__device__ __forceinline__ void gll16(const u16* g, u16* l) {
  __builtin_amdgcn_global_load_lds(
      (const __attribute__((address_space(1))) u32*)(g),
      (__attribute__((address_space(3))) u32*)(l), 16, 0, 0);
}

// ---------- merged prep ----------
// bid 0: flags+params; 1..12: BVS (gk=bid-1); 13..44: BCS (ks=bid-13);
// 45..172: cvt; 173..556: fidx; 557..813: negvar
__global__ __launch_bounds__(256) void k_prep(
    const void* vars, const int* __restrict__ lits, const void* negm, const void* vval,
    const void* Wn, const void* bn, const void* femb,
    const void* W1v, const void* b1v, const void* W2v, const void* b2v,
    const void* W1c, const void* b1c, const void* W2c, const void* b2c,
    int* flags, float* pbuf, u16* wsB) {
  __shared__ int s_cnt[4], s_big[4];
  __shared__ __align__(16) u16 shbuf[4608];  // transpose tiles / Wn^T
  const int t = threadIdx.x;
  {
    const u32 w = ((const u32*)vars)[t];
    const u32 e = (w >> 7) & 0xFF;
    const unsigned long long bal = __ballot(e >= 0x6E && e <= 0x8E);
    const u32 bw = ((const u32*)vval)[t];
    const unsigned long long bb = __ballot(bw > 1u);
    if ((t & 63) == 0) { s_cnt[t >> 6] = __popcll(bal); s_big[t >> 6] = (bb != 0ull); }
  }
  __syncthreads();
  const int fdt = (s_cnt[0] + s_cnt[1] + s_cnt[2] + s_cnt[3]) >= 192;
  const int bdt = (s_big[0] | s_big[1] | s_big[2] | s_big[3]);
  const int bid = blockIdx.x;

  if (bid == 0) {
    if (t == 0) { flags[0] = fdt; flags[1] = bdt; }
    if (t < 64) {
      const void* src[6] = {bn, femb, b1v, b2v, b1c, b2c};
      const int off[6] = {PB_BN, PB_FE, PB_B1V, PB_B2V, PB_B1C, PB_B2C};
      for (int j = 0; j < 6; j++) pbuf[off[j] + t] = ldf(src[j], t, fdt);
      wsB[U_VARSB + NV * 64 + t] = fdt ? ((const u16*)femb)[t] : f2b(((const float*)femb)[t]);
    }
  } else if (bid < 45) {
    // coalesced weight transpose: tile = 32 k-rows x 64 n of TWO sources
    const int isV = (bid < 13);
    const int kt = isV ? (bid - 1) : (bid - 13);    // k-tile index
    const void* s1 = isV ? W1v : W1c;
    const void* s2 = isV ? W2v : W2c;
    const int kbase = kt * 32;
    // load coalesced into LDS tiles T[src][k'][65]
#pragma unroll
    for (int j = 0; j < 8; j++) {
      const int i = j * 256 + t;                    // 0..2047
      const int kp = i >> 6, n = i & 63;
      shbuf[kp * 65 + n] = f2b(ldf(s1, (kbase + kp) * 64 + n, fdt));
      shbuf[2080 + kp * 65 + n] = f2b(ldf(s2, (kbase + kp) * 64 + n, fdt));
    }
    __syncthreads();
    // write swizzled, coalesced: chunk c -> [nt][ln][8]
    const int dst = isV ? (U_BVS + kt * 4096) : (U_BCS + kt * 4096);
#pragma unroll
    for (int cc = 0; cc < 2; cc++) {
      const int c = cc * 256 + t;                   // 0..511
      const int nt = c >> 6, ln = c & 63;
      const u16* T = shbuf + (nt >> 2) * 2080;
      const int n6 = (nt & 3) * 16 + (ln & 15);
      const int k0 = (ln >> 4) * 8;
      u16 o[8];
#pragma unroll
      for (int j = 0; j < 8; j++) o[j] = T[(k0 + j) * 65 + n6];
      *(short8*)(wsB + dst + c * 8) = *(short8*)o;
    }
  } else if (bid < 173) {
    const int c8 = ((bid - 45) * 256 + t) * 4;
#pragma unroll
    for (int cc = 0; cc < 4; cc++) {
      u16 o[8];
      if (fdt) {
        *(short8*)o = ((const short8*)vars)[c8 + cc];
      } else {
        const float* f = (const float*)vars + (c8 + cc) * 8;
#pragma unroll
        for (int j = 0; j < 8; j++) o[j] = f2b(f[j]);
      }
      *(short8*)(wsB + U_VARSB + (c8 + cc) * 8) = *(short8*)o;
    }
  } else if (bid < 557) {
    const int i0 = ((bid - 173) * 256 + t) * 16;
    u16 o[16];
    const int4* lp = (const int4*)(lits + i0);
    if (!bdt) {
      const int4* vp = (const int4*)((const int*)vval + i0);
      const int4* np = (const int4*)((const int*)negm + i0);
#pragma unroll
      for (int c4 = 0; c4 < 4; c4++) {
        const int4 L = lp[c4], V = vp[c4], N = np[c4];
        o[c4 * 4 + 0] = (u16)(V.x ? (L.x + (N.x ? (NV + 1) : 0)) : NV);
        o[c4 * 4 + 1] = (u16)(V.y ? (L.y + (N.y ? (NV + 1) : 0)) : NV);
        o[c4 * 4 + 2] = (u16)(V.z ? (L.z + (N.z ? (NV + 1) : 0)) : NV);
        o[c4 * 4 + 3] = (u16)(V.w ? (L.w + (N.w ? (NV + 1) : 0)) : NV);
      }
    } else {
      union { int4 v; signed char b[16]; } V, N;
      V.v = *(const int4*)((const signed char*)vval + i0);
      N.v = *(const int4*)((const signed char*)negm + i0);
#pragma unroll
      for (int c4 = 0; c4 < 4; c4++) {
        const int4 L = lp[c4];
        o[c4 * 4 + 0] = (u16)(V.b[c4 * 4 + 0] ? (L.x + (N.b[c4 * 4 + 0] ? (NV + 1) : 0)) : NV);
        o[c4 * 4 + 1] = (u16)(V.b[c4 * 4 + 1] ? (L.y + (N.b[c4 * 4 + 1] ? (NV + 1) : 0)) : NV);
        o[c4 * 4 + 2] = (u16)(V.b[c4 * 4 + 2] ? (L.z + (N.b[c4 * 4 + 2] ? (NV + 1) : 0)) : NV);
        o[c4 * 4 + 3] = (u16)(V.b[c4 * 4 + 3] ? (L.w + (N.b[c4 * 4 + 3] ? (NV + 1) : 0)) : NV);
      }
    }
    *(short8*)(wsB + U_FIDX + i0) = *(short8*)o;
    *(short8*)(wsB + U_FIDX + i0 + 8) = *(short8*)(o + 8);
  } else {
    // negvar: rows rowbase..rowbase+63; coalesced Wn load + LDS transpose (stride 72)
    const int lane = t & 63, wv = t >> 6;
    const int col = lane & 15, quad = lane >> 4, q8 = quad * 8;
    const int rowbase = (bid - 557) * 64 + wv * 16;
#pragma unroll
    for (int j = 0; j < 16; j++) {
      const int i = j * 256 + t;                    // coalesced over Wn
      const int k = i >> 6, n = i & 63;
      shbuf[n * 72 + k] = f2b(ldf(Wn, i, fdt));     // Wn^T, padded stride
    }
    __syncthreads();
    const int arow = min(rowbase + col, NV);
    short8 a[2];
    if (fdt) {
      const u16* src = (arow == NV) ? (const u16*)femb : (const u16*)vars + arow * 64;
      a[0] = *(const short8*)(src + q8);
      a[1] = *(const short8*)(src + 32 + q8);
    } else {
      const float* src = (arow == NV) ? (const float*)femb : (const float*)vars + arow * 64;
      u16 tmp[16];
#pragma unroll
      for (int j = 0; j < 8; j++) tmp[j] = f2b(src[q8 + j]);
#pragma unroll
      for (int j = 0; j < 8; j++) tmp[8 + j] = f2b(src[32 + q8 + j]);
      a[0] = *(short8*)tmp;
      a[1] = *(short8*)(tmp + 8);
    }
    f32x4 acc[4];
#pragma unroll
    for (int nt = 0; nt < 4; nt++) acc[nt] = (f32x4){0.f, 0.f, 0.f, 0.f};
#pragma unroll
    for (int ks = 0; ks < 2; ks++) {
#pragma unroll
      for (int nt = 0; nt < 4; nt++) {
        const short8 b = *(const short8*)(shbuf + (nt * 16 + col) * 72 + ks * 32 + q8);
        acc[nt] = __builtin_amdgcn_mfma_f32_16x16x32_bf16(a[ks], b, acc[nt], 0, 0, 0);
      }
    }
#pragma unroll
    for (int reg = 0; reg < 4; reg++) {
      const int r = rowbase + quad * 4 + reg;
      if (r <= NV) {
#pragma unroll
        for (int nt = 0; nt < 4; nt++) {
          const int d = nt * 16 + col;
          wsB[U_NEGB + r * 64 + d] = f2b(acc[nt][reg] + ldf(bn, d, fdt));
        }
      }
    }
  }
}

// ---------- fused clause + var combiner: 4 vars/wave, 16 vars/block (r11 verbatim) ----------
__global__ __launch_bounds__(256, 2) void k_main(
    const void* __restrict__ vars, const void* __restrict__ cval,
    const float* __restrict__ pbuf, const int* __restrict__ flags,
    const u16* __restrict__ wsB, void* __restrict__ outv) {
  __shared__ __align__(16) u16 smem[24576];
  __shared__ float ps[16][4];
  __shared__ int hcS[16];

  const int tid = threadIdx.x, lane = tid & 63, wv = tid >> 6;
  const int col = lane & 15, quad = lane >> 4, q8 = quad * 8;
  const int fdt = flags[0], bdt = flags[1];
  const int vbase = (blockIdx.x * 4 + wv) * 4;
  const int v0 = blockIdx.x * 16;

  u32 r2_[4][3];
#pragma unroll
  for (int v4 = 0; v4 < 4; v4++)
#pragma unroll
    for (int i = 0; i < 3; i++)
      r2_[v4][i] = *(const u32*)(wsB + U_FIDX + (vbase + v4) * 96 + col * 6 + i * 2);

  const int cv = ldmask(cval, vbase * 16 + lane, bdt);
  const unsigned long long bal = __ballot(cv != 0);
  if (lane < 4) hcS[wv * 4 + lane] = ((bal >> (lane * 16)) & 0xFFFFull) != 0;

  f32x4 acc[4][8];
#pragma unroll
  for (int v4 = 0; v4 < 4; v4++)
#pragma unroll
    for (int nt = 0; nt < 8; nt++) acc[v4][nt] = (f32x4){0.f, 0.f, 0.f, 0.f};

#pragma unroll
  for (int j = 0; j < 6; j++) {
    const int cl = wv * 6 + j;
    gll16(wsB + U_BVS + cl * 512 + lane * 8, &smem[cl * 512]);
  }
  short8 a_cur[4], a_nxt[4];
#pragma unroll
  for (int v4 = 0; v4 < 4; v4++) {
    const int idx = (int)(r2_[v4][0] & 0xFFFFu);
    a_cur[v4] = *(const short8*)(wsB + U_VARSB + idx * 64 + q8);
  }
  __syncthreads();

  for (int q = 0; q < 4; q++) {
    if (q < 3) {
#pragma unroll
      for (int j = 0; j < 6; j++) {
        const int cl = wv * 6 + j;
        gll16(wsB + U_BVS + (q + 1) * 12288 + cl * 512 + lane * 8,
              &smem[((q + 1) & 1) * 12288 + cl * 512]);
      }
    }
#pragma unroll
    for (int ksl = 0; ksl < 3; ksl++) {
      const int gk = q * 3 + ksl;
      if (gk < 11) {
        const int gn = gk + 1;
        const int goff = (gn & 1) * 32 + q8;
        const int pi = gn >> 2, ph = (gn >> 1) & 1;
#pragma unroll
        for (int v4 = 0; v4 < 4; v4++) {
          const int idx = (int)((r2_[v4][pi] >> (ph * 16)) & 0xFFFFu);
          a_nxt[v4] = *(const short8*)(wsB + U_VARSB + idx * 64 + goff);
        }
      }
#pragma unroll
      for (int nt = 0; nt < 8; nt++) {
        const short8 b = *(const short8*)(&smem[(q & 1) * 12288 + (ksl * 8 + nt) * 512 + lane * 8]);
#pragma unroll
        for (int v4 = 0; v4 < 4; v4++)
          acc[v4][nt] = __builtin_amdgcn_mfma_f32_16x16x32_bf16(a_cur[v4], b, acc[v4][nt], 0, 0, 0);
      }
#pragma unroll
      for (int v4 = 0; v4 < 4; v4++) a_cur[v4] = a_nxt[v4];
    }
    if (q < 3) __syncthreads();
  }
  __syncthreads();

  {
    float b1l[4], b2l[4], truel[4];
#pragma unroll
    for (int nt = 0; nt < 4; nt++) {
      const int d = nt * 16 + col;
      b1l[nt] = pbuf[PB_B1V + d];
      b2l[nt] = pbuf[PB_B2V + d];
      truel[nt] = ldbf(wsB, U_NEGB + NV * 64 + d);
    }
#pragma unroll
    for (int v4 = 0; v4 < 4; v4++) {
      const u32 vmask = (u32)((bal >> (v4 * 16)) & 0xFFFFull);
      const int vloc = wv * 4 + v4;
#pragma unroll
      for (int reg = 0; reg < 4; reg++) {
        const int c = quad * 4 + reg;
        float hh[4], ss = 0.f;
#pragma unroll
        for (int nt = 0; nt < 4; nt++) {
          hh[nt] = 1.0f / (1.0f + __expf(-(acc[v4][nt][reg] + b1l[nt]))) + acc[v4][nt + 4][reg] + b2l[nt];
          ss += hh[nt] * hh[nt];
        }
        ss += __shfl_xor(ss, 1, 64); ss += __shfl_xor(ss, 2, 64);
        ss += __shfl_xor(ss, 4, 64); ss += __shfl_xor(ss, 8, 64);
        const float sc = 1.0f / sqrtf(ss);
        const int valid = (vmask >> c) & 1;
#pragma unroll
        for (int nt = 0; nt < 4; nt++) {
          const float o = valid ? hh[nt] * sc : truel[nt];
          const int l2 = (nt * 2 + (col >> 3)) & 3;
          smem[(c * 2 + (nt >> 1)) * 512 + (l2 * 16 + vloc) * 8 + (col & 7)] = f2b(o);
        }
      }
    }
  }
  __syncthreads();

  f32x4 acc1 = (f32x4){0.f, 0.f, 0.f, 0.f}, acc2 = (f32x4){0.f, 0.f, 0.f, 0.f};
#pragma unroll 8
  for (int ks = 0; ks < 32; ks++) {
    const short8 a = *(const short8*)(&smem[ks * 512 + lane * 8]);
    const short8 b1 = *(const short8*)(wsB + U_BCS + (ks * 8 + wv) * 512 + lane * 8);
    const short8 b2 = *(const short8*)(wsB + U_BCS + (ks * 8 + wv + 4) * 512 + lane * 8);
    acc1 = __builtin_amdgcn_mfma_f32_16x16x32_bf16(a, b1, acc1, 0, 0, 0);
    acc2 = __builtin_amdgcn_mfma_f32_16x16x32_bf16(a, b2, acc2, 0, 0, 0);
  }

  const int d = wv * 16 + col;
  const float b1c_d = pbuf[PB_B1C + d], b2c_d = pbuf[PB_B2C + d];
  float h[4];
#pragma unroll
  for (int reg = 0; reg < 4; reg++) {
    h[reg] = 1.0f / (1.0f + __expf(-(acc1[reg] + b1c_d))) + acc2[reg] + b2c_d;
    float ssp = h[reg] * h[reg];
    ssp += __shfl_xor(ssp, 1, 64); ssp += __shfl_xor(ssp, 2, 64);
    ssp += __shfl_xor(ssp, 4, 64); ssp += __shfl_xor(ssp, 8, 64);
    if (col == 0) ps[quad * 4 + reg][wv] = ssp;
  }
  __syncthreads();
#pragma unroll
  for (int reg = 0; reg < 4; reg++) {
    const int r = quad * 4 + reg;
    const float tot = ps[r][0] + ps[r][1] + ps[r][2] + ps[r][3];
    float o = h[reg] * (1.0f / sqrtf(tot));
    const int oi = (v0 + r) * 64 + d;
    if (hcS[r]) {
      if (fdt) ((u16*)outv)[oi] = f2b(o);
      else ((float*)outv)[oi] = o;
    } else {
      if (fdt) ((u16*)outv)[oi] = ((const u16*)vars)[oi];
      else ((float*)outv)[oi] = ((const float*)vars)[oi];
    }
  }
}

extern "C" void kernel_launch(void* const* d_in, const int* in_sizes, int n_in,
                              void* d_out, int out_size, void* d_ws, size_t ws_size,
                              hipStream_t stream) {
  const void* vars = d_in[0];
  const int* lits = (const int*)d_in[1];
  const void* negm = d_in[2];
  const void* vval = d_in[3];
  const void* cvalid = d_in[4];
  const void* Wn = d_in[5];
  const void* bn = d_in[6];
  const void* femb = d_in[7];
  const void* W1v = d_in[8];
  const void* b1v = d_in[9];
  const void* W2v = d_in[10];
  const void* b2v = d_in[11];
  const void* W1c = d_in[12];
  const void* b1c = d_in[13];
  const void* W2c = d_in[14];
  const void* b2c = d_in[15];

  int* flags = (int*)d_ws;
  float* pbuf = (float*)((char*)d_ws + 256);
  u16* wsB = (u16*)d_ws;

  k_prep<<<814, 256, 0, stream>>>(vars, lits, negm, vval, Wn, bn, femb,
                                  W1v, b1v, W2v, b2v, W1c, b1c, W2c, b2c,
                                  flags, pbuf, wsB);
  k_main<<<NV / 16, 256, 0, stream>>>(vars, cvalid, pbuf, flags, wsB, d_out);
}